// Round 14
// baseline (110.180 us; speedup 1.0000x reference)
//
#include <hip/hip_runtime.h>
#include <hip/hip_bf16.h>
#include <stdint.h>

typedef __bf16 bf16x8 __attribute__((ext_vector_type(8)));
typedef __bf16 bf16x4 __attribute__((ext_vector_type(4)));
typedef float  f32x4  __attribute__((ext_vector_type(4)));

#define GLOBAL_AS __attribute__((address_space(1)))
#define LDS_AS    __attribute__((address_space(3)))

__device__ __forceinline__ void gld_lds16(const __bf16* g, __bf16* l) {
  __builtin_amdgcn_global_load_lds((GLOBAL_AS void*)g, (LDS_AS void*)l, 16, 0, 0);
}

// q pre-scale: 1/sqrt(64) * log2(e)  (softmax runs in exp2 domain)
#define QSCALE 0.18033688011116029f

__device__ __forceinline__ unsigned pk2(float a, float b) {
  unsigned short ua = __builtin_bit_cast(unsigned short, (__bf16)a);
  unsigned short ub = __builtin_bit_cast(unsigned short, (__bf16)b);
  return (unsigned)ua | ((unsigned)ub << 16);
}

union PackU { unsigned u[4]; bf16x8 v; };

// ---------------- cast f32 -> bf16 (vectorized) ----------------
__global__ __launch_bounds__(256) void cast_bf16_kernel(const float* __restrict__ src,
                                                        __bf16* __restrict__ dst, int n)
{
  int i = (blockIdx.x * 256 + threadIdx.x) * 8;
  if (i >= n) return;
  float4 a = *(const float4*)(src + i);
  float4 b = *(const float4*)(src + i + 4);
  bf16x8 o;
  o[0]=(__bf16)a.x; o[1]=(__bf16)a.y; o[2]=(__bf16)a.z; o[3]=(__bf16)a.w;
  o[4]=(__bf16)b.x; o[5]=(__bf16)b.y; o[6]=(__bf16)b.z; o[7]=(__bf16)b.w;
  *(bf16x8*)(dst + i) = o;
}

// ---------------- transpose f32[R][C] -> bf16[C][R] ----------------
__global__ __launch_bounds__(256) void transpose_cast_kernel(const float* __restrict__ src,
                                                             __bf16* __restrict__ dst,
                                                             int R, int C)
{
  __shared__ float tile[32][33];
  int c0 = blockIdx.x * 32, r0 = blockIdx.y * 32;
  int tx = threadIdx.x & 31, ty = threadIdx.x >> 5;
  #pragma unroll
  for (int i = 0; i < 32; i += 8)
    tile[ty + i][tx] = src[(size_t)(r0 + ty + i) * C + (c0 + tx)];
  __syncthreads();
  #pragma unroll
  for (int i = 0; i < 32; i += 8)
    dst[(size_t)(c0 + ty + i) * R + (r0 + tx)] = (__bf16)tile[tx][ty + i];
}

// ---------------- BMx128 bf16 GEMM, BK=64, swizzled LDS ----------------
// MODE 0 (BM=128): 1D grid 768, XCD-chunked swizzle. Epilogue scatters q (pre-scaled,
// [B,H,T,D]) and K/V in MFMA-FRAGMENT layout [bh][tile][mb|nb][ks][lane][8] -- defined as
// exactly the register bytes the attn TILE (R8-verified) needs per lane, so attention
// reads them with single coalesced dwordx4 loads and needs NO LDS at all.
// MODE 1: 2D grid, f32 [M,N] output.
template<int MODE, int BM>
__global__ __launch_bounds__(256, (BM == 128 ? 3 : 2))
void gemm_kernel(const __bf16* __restrict__ A,
                 const __bf16* __restrict__ Bt,
                 const float*  __restrict__ bias,
                 float* __restrict__ outF,
                 __bf16* __restrict__ qb,
                 __bf16* __restrict__ kfr,
                 __bf16* __restrict__ vfr,
                 int M, int N, int K)
{
  __shared__ __bf16 As[BM * 64];
  __shared__ __bf16 Bs[128 * 64];
  const int tid  = threadIdx.x;
  const int wave = tid >> 6, lane = tid & 63;
  const int lo = lane & 15, g4 = lane >> 4;
  int bm, bn;
  if (MODE == 0) {
    int bid = blockIdx.x;                        // 0..767
    int bm_i = (bid & 7) * 4 + ((bid >> 3) & 3); // xcd-chunked bm
    int bn_i = bid >> 5;                         // 0..23
    bm = bm_i * 128; bn = bn_i * 128;
  } else {
    bm = blockIdx.y * BM; bn = blockIdx.x * 128;
  }
  const int wr = (wave >> 1) * (BM / 2);
  const int wc = (wave & 1) * 64;
  constexpr int MF = BM / 32;

  f32x4 acc[MF][4] = {};

  const int nkt = K >> 6;
  for (int kt = 0; kt < nkt; ++kt) {
    const int k0 = kt << 6;
    __syncthreads();
    #pragma unroll
    for (int j = 0; j < BM / 32; ++j) {
      int c = j * 256 + tid;
      int r = c >> 3, cc = c & 7;
      int cs = cc ^ (r & 7);
      gld_lds16(A + (size_t)(bm + r) * K + (k0 + cs * 8), As + c * 8);
    }
    #pragma unroll
    for (int j = 0; j < 4; ++j) {
      int c = j * 256 + tid;
      int r = c >> 3, cc = c & 7;
      int cs = cc ^ (r & 7);
      gld_lds16(Bt + (size_t)(bn + r) * K + (k0 + cs * 8), Bs + c * 8);
    }
    __syncthreads();
    #pragma unroll
    for (int ks = 0; ks < 2; ++ks) {
      bf16x8 af[MF], bfr[4];
      #pragma unroll
      for (int mf = 0; mf < MF; ++mf) {
        int row = wr + mf * 16 + lo;
        int ch = (ks * 4 + g4) ^ (row & 7);
        af[mf] = *(const bf16x8*)(As + row * 64 + ch * 8);
      }
      #pragma unroll
      for (int nf = 0; nf < 4; ++nf) {
        int row = wc + nf * 16 + lo;
        int ch = (ks * 4 + g4) ^ (row & 7);
        bfr[nf] = *(const bf16x8*)(Bs + row * 64 + ch * 8);
      }
      #pragma unroll
      for (int mf = 0; mf < MF; ++mf)
        #pragma unroll
        for (int nf = 0; nf < 4; ++nf)
          acc[mf][nf] = __builtin_amdgcn_mfma_f32_16x16x32_bf16(af[mf], bfr[nf], acc[mf][nf], 0, 0, 0);
    }
  }

  float bv[4];
  #pragma unroll
  for (int nf = 0; nf < 4; ++nf) bv[nf] = bias[bn + wc + nf * 16 + lo];

  if (MODE == 1) {
    #pragma unroll
    for (int mf = 0; mf < MF; ++mf)
      #pragma unroll
      for (int nf = 0; nf < 4; ++nf) {
        int col = bn + wc + nf * 16 + lo;
        #pragma unroll
        for (int j = 0; j < 4; ++j) {
          int row = bm + wr + mf * 16 + g4 * 4 + j;
          outF[(size_t)row * N + col] = acc[mf][nf][j] + bv[nf];
        }
      }
  } else {
    #pragma unroll
    for (int mf = 0; mf < MF; ++mf) {
      const int tbase = bm + wr + mf * 16 + g4 * 4;
      const int b = tbase >> 11, t = tbase & 2047;
      const int i_t = t >> 6;            // kv tile
      #pragma unroll
      for (int nf = 0; nf < 4; ++nf) {
        int n = bn + wc + nf * 16 + lo;
        int sel = n >> 10, hd = n & 1023;
        int h = hd >> 6, d = hd & 63;
        size_t bh = (size_t)(b * 16 + h);
        if (sel == 2) {
          // V fragment: [bh][i][nb=d>>4][ks=tt>>5][lane=gv*16+(d&15)][j=tt&7]
          int tt = t & 63;
          int ks = tt >> 5, gv = (tt >> 3) & 3, j0 = tt & 7;
          bf16x4 pv;
          #pragma unroll
          for (int j = 0; j < 4; ++j) pv[j] = (__bf16)(acc[mf][nf][j] + bv[nf]);
          *(bf16x4*)(vfr + bh * 131072 + i_t * 4096 + (d >> 4) * 1024 + ks * 512
                     + (gv * 16 + (d & 15)) * 8 + j0) = pv;
        } else if (sel == 0) {
          #pragma unroll
          for (int j = 0; j < 4; ++j)
            qb[(bh * 2048 + (size_t)(t + j)) * 64 + d] = (__bf16)((acc[mf][nf][j] + bv[nf]) * QSCALE);
        } else {
          // K fragment: [bh][i][mb][ks=d>>5][lane=gk*16+m][j=d&7]
          //   tt bits: mb = 2*b5 + b2;  m = 8*b4 + 4*b3 + (tt&3)
          int ksd = d >> 5, gk = (d >> 3) & 3, jd = d & 7;
          #pragma unroll
          for (int j = 0; j < 4; ++j) {
            int tt = (t + j) & 63;
            int mb = 2 * (tt >> 5) + ((tt >> 2) & 1);
            int m  = 8 * ((tt >> 4) & 1) + 4 * ((tt >> 3) & 1) + (tt & 3);
            kfr[bh * 131072 + i_t * 4096 + mb * 1024 + ksd * 512 + (gk * 16 + m) * 8 + jd]
                = (__bf16)(acc[mf][nf][j] + bv[nf]);
          }
        }
      }
    }
  }
}

// ---------------- causal flash attention: LDS-FREE, fragment-layout K/V ----------------
// 1024 blocks x 4 waves (16 q/wave, 64-row strip), R8 complementary co-residency.
// K/V arrive pre-arranged in MFMA-fragment order: per wave-tile, 16 perfectly-coalesced
// 1KB dwordx4 loads from L1/L2 (per-XCD set 2MB < L2). NO __shared__, NO barriers,
// NO staging, NO swizzle math -- the TILE body is byte-identical to the verified R8
// kernel (same kv labels for mask/pack/V-pairing), only the operand source changed.
// Fixed-max exp2 softmax, ones-MFMA row sums.
__global__ __launch_bounds__(256, 4)
void attn_kernel(const __bf16* __restrict__ qg, const __bf16* __restrict__ kf_,
                 const __bf16* __restrict__ vf_, __bf16* __restrict__ yg)
{
  const int n = blockIdx.x;
  const int xcd = n & 7;
  const int w = n >> 3;              // 0..127 within xcd
  const int quad = w >> 5;           // 0..3 (co-residency quadrant)
  const int r = w & 31;
  const int bh = xcd + 8 * (r & 3);
  const int p = r >> 2;              // 0..7
  int strip;
  if      (quad == 0) strip = p;
  else if (quad == 1) strip = 31 - p;
  else if (quad == 2) strip = 8 + p;
  else                strip = 23 - p;
  const int b = bh >> 4, h = bh & 15;

  const int tid  = threadIdx.x;
  const int wave = tid >> 6;
  const int lane = tid & 63;
  const int l15  = lane & 15;
  const int g    = lane >> 4;

  const __bf16* qbase = qg + (size_t)bh * 2048 * 64;
  const __bf16* kb = kf_ + (size_t)bh * 131072 + lane * 8;
  const __bf16* vb = vf_ + (size_t)bh * 131072 + lane * 8;

  const int q16 = strip * 64 + wave * 16 + l15;
  const bf16x8 qf0 = *(const bf16x8*)(qbase + (size_t)q16 * 64 + g * 8);
  const bf16x8 qf1 = *(const bf16x8*)(qbase + (size_t)q16 * 64 + 32 + g * 8);

  f32x4 o0 = {}, o1 = {}, o2 = {}, o3 = {}, osum = {};

  bf16x8 ones;
  #pragma unroll
  for (int j = 0; j < 8; ++j) ones[j] = (__bf16)1.0f;

  for (int i = 0; i <= strip; ++i) {
    const __bf16* kt = kb + i * 4096;

    // ---- S = K * Q^T : same kv labels as R8 (s_mb[r] <-> kv = 32*(mb>>1)+4*(mb&1)+8g+r) ----
    bf16x8 k00 = *(const bf16x8*)(kt);
    bf16x8 k01 = *(const bf16x8*)(kt + 512);
    bf16x8 k10 = *(const bf16x8*)(kt + 1024);
    bf16x8 k11 = *(const bf16x8*)(kt + 1536);
    bf16x8 k20 = *(const bf16x8*)(kt + 2048);
    bf16x8 k21 = *(const bf16x8*)(kt + 2560);
    bf16x8 k30 = *(const bf16x8*)(kt + 3072);
    bf16x8 k31 = *(const bf16x8*)(kt + 3584);

    f32x4 s0 = {}, s1 = {}, s2 = {}, s3 = {};
    s0 = __builtin_amdgcn_mfma_f32_16x16x32_bf16(k00, qf0, s0, 0, 0, 0);
    s0 = __builtin_amdgcn_mfma_f32_16x16x32_bf16(k01, qf1, s0, 0, 0, 0);
    s1 = __builtin_amdgcn_mfma_f32_16x16x32_bf16(k10, qf0, s1, 0, 0, 0);
    s1 = __builtin_amdgcn_mfma_f32_16x16x32_bf16(k11, qf1, s1, 0, 0, 0);
    s2 = __builtin_amdgcn_mfma_f32_16x16x32_bf16(k20, qf0, s2, 0, 0, 0);
    s2 = __builtin_amdgcn_mfma_f32_16x16x32_bf16(k21, qf1, s2, 0, 0, 0);
    s3 = __builtin_amdgcn_mfma_f32_16x16x32_bf16(k30, qf0, s3, 0, 0, 0);
    s3 = __builtin_amdgcn_mfma_f32_16x16x32_bf16(k31, qf1, s3, 0, 0, 0);

    // ---- V fragment loads (independent; hide under mask/exp2/pack) ----
    const __bf16* vt = vb + i * 4096;
    bf16x8 v00 = *(const bf16x8*)(vt);
    bf16x8 v01 = *(const bf16x8*)(vt + 512);
    bf16x8 v10 = *(const bf16x8*)(vt + 1024);
    bf16x8 v11 = *(const bf16x8*)(vt + 1536);
    bf16x8 v20 = *(const bf16x8*)(vt + 2048);
    bf16x8 v21 = *(const bf16x8*)(vt + 2560);
    bf16x8 v30 = *(const bf16x8*)(vt + 3072);
    bf16x8 v31 = *(const bf16x8*)(vt + 3584);

    if (i == strip) {                    // causal mask on diagonal tile
      const int qr = wave * 16 + l15;
      #pragma unroll
      for (int r2 = 0; r2 < 4; ++r2) {
        if (8 * g + r2          > qr) s0[r2] = -3.0e38f;
        if (8 * g + 4 + r2      > qr) s1[r2] = -3.0e38f;
        if (32 + 8 * g + r2     > qr) s2[r2] = -3.0e38f;
        if (32 + 8 * g + 4 + r2 > qr) s3[r2] = -3.0e38f;
      }
    }

    // ---- fixed-max softmax: P = exp2(S) directly (|S| <~ 9 << 127) ----
    #pragma unroll
    for (int r2 = 0; r2 < 4; ++r2) s0[r2] = exp2f(s0[r2]);
    #pragma unroll
    for (int r2 = 0; r2 < 4; ++r2) s1[r2] = exp2f(s1[r2]);
    #pragma unroll
    for (int r2 = 0; r2 < 4; ++r2) s2[r2] = exp2f(s2[r2]);
    #pragma unroll
    for (int r2 = 0; r2 < 4; ++r2) s3[r2] = exp2f(s3[r2]);

    // ---- P -> A-fragments: pure in-lane packing ----
    PackU pa0, pa1;
    pa0.u[0] = pk2(s0[0], s0[1]); pa0.u[1] = pk2(s0[2], s0[3]);
    pa0.u[2] = pk2(s1[0], s1[1]); pa0.u[3] = pk2(s1[2], s1[3]);
    pa1.u[0] = pk2(s2[0], s2[1]); pa1.u[1] = pk2(s2[2], s2[3]);
    pa1.u[2] = pk2(s3[0], s3[1]); pa1.u[3] = pk2(s3[2], s3[3]);

    // ---- row sums via ones-MFMA ----
    osum = __builtin_amdgcn_mfma_f32_16x16x32_bf16(pa0.v, ones, osum, 0, 0, 0);
    osum = __builtin_amdgcn_mfma_f32_16x16x32_bf16(pa1.v, ones, osum, 0, 0, 0);

    // ---- O += P V (same pairing as R8: pa0 <-> ks=0 chunk, pa1 <-> ks=1) ----
    o0 = __builtin_amdgcn_mfma_f32_16x16x32_bf16(pa0.v, v00, o0, 0, 0, 0);
    o0 = __builtin_amdgcn_mfma_f32_16x16x32_bf16(pa1.v, v01, o0, 0, 0, 0);
    o1 = __builtin_amdgcn_mfma_f32_16x16x32_bf16(pa0.v, v10, o1, 0, 0, 0);
    o1 = __builtin_amdgcn_mfma_f32_16x16x32_bf16(pa1.v, v11, o1, 0, 0, 0);
    o2 = __builtin_amdgcn_mfma_f32_16x16x32_bf16(pa0.v, v20, o2, 0, 0, 0);
    o2 = __builtin_amdgcn_mfma_f32_16x16x32_bf16(pa1.v, v21, o2, 0, 0, 0);
    o3 = __builtin_amdgcn_mfma_f32_16x16x32_bf16(pa0.v, v30, o3, 0, 0, 0);
    o3 = __builtin_amdgcn_mfma_f32_16x16x32_bf16(pa1.v, v31, o3, 0, 0, 0);
  }

  // ---- epilogue: O / l, scatter ----
  #pragma unroll
  for (int r2 = 0; r2 < 4; ++r2) {
    float il = 1.0f / osum[r2];
    int trow = strip * 64 + wave * 16 + 4 * g + r2;
    __bf16* dst = yg + ((size_t)(b * 2048 + trow)) * 1024 + h * 64;
    dst[l15]      = (__bf16)(o0[r2] * il);
    dst[16 + l15] = (__bf16)(o1[r2] * il);
    dst[32 + l15] = (__bf16)(o2[r2] * il);
    dst[48 + l15] = (__bf16)(o3[r2] * il);
  }
}

extern "C" void kernel_launch(void* const* d_in, const int* in_sizes, int n_in,
                              void* d_out, int out_size, void* d_ws, size_t ws_size,
                              hipStream_t stream)
{
  const float* x      = (const float*)d_in[0];
  const float* w_attn = (const float*)d_in[1];
  const float* b_attn = (const float*)d_in[2];
  const float* w_proj = (const float*)d_in[3];
  const float* b_proj = (const float*)d_in[4];
  float* out = (float*)d_out;

  __bf16* xb  = (__bf16*)d_ws;                      // [4096,1024]
  __bf16* waT = xb  + (size_t)4096 * 1024;          // [3072,1024]  (w_attn^T)
  __bf16* wpT = waT + (size_t)3072 * 1024;          // [1024,1024]  (w_proj^T)
  __bf16* qb  = wpT + (size_t)1024 * 1024;          // [B,H,T,D] (pre-scaled)
  __bf16* kfr = qb  + (size_t)32 * 2048 * 64;       // K fragments [bh][32][4][2][64][8]
  __bf16* vfr = kfr + (size_t)32 * 2048 * 64;       // V fragments [bh][32][4][2][64][8]
  __bf16* yb  = vfr + (size_t)32 * 2048 * 64;       // [4096,1024]

  cast_bf16_kernel<<<2048, 256, 0, stream>>>(x, xb, 4096 * 1024);
  transpose_cast_kernel<<<dim3(96, 32), 256, 0, stream>>>(w_attn, waT, 1024, 3072);
  transpose_cast_kernel<<<dim3(32, 32), 256, 0, stream>>>(w_proj, wpT, 1024, 1024);
  gemm_kernel<0, 128><<<768, 256, 0, stream>>>(xb, waT, b_attn, nullptr,
                                               qb, kfr, vfr, 4096, 3072, 1024);
  attn_kernel<<<1024, 256, 0, stream>>>(qb, kfr, vfr, yb);
  gemm_kernel<1, 64><<<dim3(8, 64), 256, 0, stream>>>(yb, wpT, b_proj, out,
                                                      nullptr, nullptr, nullptr, 4096, 1024, 1024);
}